// Round 8
// baseline (331.885 us; speedup 1.0000x reference)
//
#include <hip/hip_runtime.h>
#include <hip/hip_bf16.h>
#include <math.h>

#define LSEQ 2048
#define HD   512
#define NST  32
#define LC   32
#define NCHK 64   /* LSEQ/LC */
#define SUP  8    /* chunks per superchunk */
#define NSUP 8    /* NCHK/SUP */
#define HH   (HD * HD)

typedef __bf16 bf16;
typedef __bf16 bf16x8 __attribute__((ext_vector_type(8)));
typedef float  floatx4 __attribute__((ext_vector_type(4)));

__device__ __forceinline__ float gelu_tanh(float x) {
    float z = 0.7978845608028654f * (x + 0.044715f * x * x * x);
    float e = __expf(2.f * z);
    float th = 1.f - 2.f / (e + 1.f);   // tanh(z), saturates cleanly
    return 0.5f * x * (1.f + th);
}

__device__ __forceinline__ void make_ab(float lre, float lim, float step,
                                        float br0, float bi0,
                                        float& ar, float& ai, float& br, float& bi) {
    float s2 = 0.5f * step;
    float dr = 1.f - s2 * lre, di = -s2 * lim;      // 1 - (dt/2)Lam
    float inv = 1.f / (dr * dr + di * di);
    float blr = dr * inv, bli = -di * inv;          // BL = 1/(dr+i*di)
    float nr = 1.f + s2 * lre, ni = s2 * lim;       // 1 + (dt/2)Lam
    ar = blr * nr - bli * ni;
    ai = blr * ni + bli * nr;
    float tr = step * br0, ti = step * bi0;         // dt * B
    br = blr * tr - bli * ti;
    bi = blr * ti + bli * tr;
}

// ---------------- setup: encoder(+layer-0 stat partials) + weight cvt + prep --------
__global__ __launch_bounds__(256) void setup_kernel(
    const float* __restrict__ x,   const float* __restrict__ ew,
    const float* __restrict__ eb,  const float* __restrict__ ow,
    const float* __restrict__ o2w,
    const float* __restrict__ lre, const float* __restrict__ lim,
    const float* __restrict__ bre, const float* __restrict__ bim,
    const float* __restrict__ cre, const float* __restrict__ cim,
    const float* __restrict__ ls,
    float* __restrict__ h, bf16* __restrict__ wb,
    float2* __restrict__ cA, float2* __restrict__ cB,
    float2* __restrict__ cC, float2* __restrict__ cAp,
    float2* __restrict__ cApJ, float2* __restrict__ statP) {
    int bid = blockIdx.x, tid = threadIdx.x;
    if (bid < 4096) {                               // encoder: [L,4] @ [4,H]^T
        int idx = bid * 256 + tid;
        int t = idx >> 9, col = idx & (HD - 1);
        float4 xv = *(const float4*)(x + t * 4);
        float4 wv = *(const float4*)(ew + col * 4);
        float acc = eb[col];
        acc = fmaf(xv.x, wv.x, acc); acc = fmaf(xv.y, wv.y, acc);
        acc = fmaf(xv.z, wv.z, acc); acc = fmaf(xv.w, wv.w, acc);
        h[idx] = acc;
        float s = acc, s2 = acc * acc;
#pragma unroll
        for (int m = 1; m <= 8; m <<= 1) {
            s  += __shfl_xor(s, m, 64);
            s2 += __shfl_xor(s2, m, 64);
        }
        if ((tid & 15) == 0) statP[(size_t)t * 32 + (col >> 4)] = make_float2(s, s2);
    } else if (bid < 5120) {                        // f32 -> bf16 weights
        int b2 = bid - 4096;
        const float* src = (b2 >= 512) ? o2w : ow;
        bf16* dst = wb + (b2 >= 512 ? 4 * HH : 0);
        int i = ((b2 & 511) * 256 + tid) * 8;
        float4 a = *(const float4*)(src + i);
        float4 b = *(const float4*)(src + i + 4);
        bf16x8 o;
        o[0] = (bf16)a.x; o[1] = (bf16)a.y; o[2] = (bf16)a.z; o[3] = (bf16)a.w;
        o[4] = (bf16)b.x; o[5] = (bf16)b.y; o[6] = (bf16)b.z; o[7] = (bf16)b.w;
        *(bf16x8*)(dst + i) = o;
    } else {                                        // coefficient prep (65536 threads)
        int tg = (bid - 5120) * 256 + tid;
        int lay = tg >> 14, rem = tg & 16383;
        int ch = rem >> 5, n = rem & 31;
        float step = __expf(ls[lay * HD + ch]);
        float ar, ai, br, bi;
        make_ab(lre[tg], lim[tg], step, bre[tg], bim[tg], ar, ai, br, bi);
        float xr = ar, xi = ai;                     // Abar^LC (5 squarings)
#pragma unroll
        for (int q = 0; q < 5; ++q) { float tt = xr * xr - xi * xi; xi = 2.f * xr * xi; xr = tt; }
        int dst = (lay * NST + n) * HD + ch;
        cA[dst]  = make_float2(ar, ai);
        cB[dst]  = make_float2(br, bi);
        cC[dst]  = make_float2(2.f * cre[tg], 2.f * cim[tg]);
        cAp[dst] = make_float2(xr, xi);
        float pr = xr, pi = xi;                     // (A^LC)^j, j=1..7
#pragma unroll
        for (int jj = 0; jj < 7; ++jj) {
            cApJ[((size_t)(lay * 7 + jj) * NST + n) * HD + ch] = make_float2(pr, pi);
            float t2r = pr * xr - pi * xi;
            float t2i = pr * xi + pi * xr;
            pr = t2r; pi = t2i;
        }
    }
}

// ---------------- P1: per-superchunk block (8 waves = 8 chunks) ---------------------
// grid (32 bx, 8 sup), 512 threads. Writes WITHIN-SUPER inclusive prefixes to f.
__global__ __launch_bounds__(512, 1) void p1_kernel(
    const float* __restrict__ h, const float2* __restrict__ statP,
    const float* __restrict__ nwp, const float* __restrict__ nbp,
    const float2* __restrict__ cA, const float2* __restrict__ cB,
    const float2* __restrict__ cAp,
    float2* __restrict__ f, int lay) {
    __shared__ float tile[256 * 16];                // 16 KB raw h
    __shared__ float2 stat_s[256];                  // 2 KB
    __shared__ float2 fs[8 * 32 * 16];              // 32 KB chunk-final states
    const int tid = threadIdx.x;
    const int lane = tid & 63, w = tid >> 6;        // w = chunk within super
    const int chl = lane & 15, sub = lane >> 4;
    const int bx = blockIdx.x, sup = blockIdx.y;
    const int ch = bx * 16 + chl;

    const float* ub = h + (size_t)(sup * 256) * HD + bx * 16;
#pragma unroll
    for (int r = 0; r < 2; ++r) {
        int i = r * 512 + tid;
        int tr = i >> 2, c4 = (i & 3) * 4;
        *(float4*)(tile + tr * 16 + c4) = *(const float4*)(ub + (size_t)tr * HD + c4);
    }
    if (tid < 256) {                                // LN stats from partials
        const float4* pp = (const float4*)(statP + (size_t)(sup * 256 + tid) * 32);
        float S = 0.f, S2 = 0.f;
#pragma unroll
        for (int k = 0; k < 16; ++k) {
            float4 v = pp[k];
            S += v.x + v.z; S2 += v.y + v.w;
        }
        float m = S * (1.f / HD);
        float var = S2 * (1.f / HD) - m * m;
        stat_s[tid] = make_float2(m, rsqrtf(var + 1e-5f));
    }
    int cbase = (lay * NST + sub * 8) * HD + ch;
    float aR[8], aI[8], bR[8], bI[8];
#pragma unroll
    for (int j = 0; j < 8; ++j) {
        float2 t2 = cA[cbase + j * HD]; aR[j] = t2.x; aI[j] = t2.y;
        t2 = cB[cbase + j * HD];        bR[j] = t2.x; bI[j] = t2.y;
    }
    float gam = nwp[ch], bet = nbp[ch];
    __syncthreads();

    // local scan of chunk w, inline normalize
    const float* tp = tile + (w * LC) * 16 + chl;
    float sr[8], si[8];
#pragma unroll
    for (int j = 0; j < 8; ++j) { sr[j] = 0.f; si[j] = 0.f; }
#pragma unroll 4
    for (int t = 0; t < LC; ++t) {
        float2 st = stat_s[w * LC + t];
        float gr = gam * st.y;
        float off = fmaf(-st.x, gr, bet);
        float uu = fmaf(tp[t * 16], gr, off);
#pragma unroll
        for (int j = 0; j < 8; ++j) {
            float nr = fmaf(aR[j], sr[j], fmaf(-aI[j], si[j], bR[j] * uu));
            float ni = fmaf(aI[j], sr[j], fmaf( aR[j], si[j], bI[j] * uu));
            sr[j] = nr; si[j] = ni;
        }
    }
#pragma unroll
    for (int j = 0; j < 8; ++j)
        fs[(w * 32 + sub * 8 + j) * 16 + chl] = make_float2(sr[j], si[j]);
    __syncthreads();

    // in-block scan over the 8 chunk-finals; write within-super prefixes to f
    int n2 = tid >> 4, c2 = tid & 15;
    int chg = bx * 16 + c2;
    float2 ap = cAp[(lay * NST + n2) * HD + chg];
    const size_t CS = (size_t)NST * HD;
    float2* fo = f + (size_t)n2 * HD + chg;
    float s2r = 0.f, s2i = 0.f;
#pragma unroll
    for (int k = 0; k < 8; ++k) {
        float2 v = fs[(k * 32 + n2) * 16 + c2];
        float nr = fmaf(ap.x, s2r, fmaf(-ap.y, s2i, v.x));
        float ni = fmaf(ap.y, s2r, fmaf( ap.x, s2i, v.y));
        s2r = nr; s2i = ni;
        fo[(size_t)(sup * 8 + k) * CS] = make_float2(s2r, s2i);
    }
}

// ---------------- P3: replay; self-computed super prefix (p2 merged in) -------------
// grid (32, 16), 256 threads, 4 chunks/block.
// carry(chunk c=8k+j): S_k = exclusive scan of super finals (<=7 steps, in-thread);
//                      j==0 -> S_k; j>0 -> f_w[c-1] + (A^LC)^j * S_k.
__global__ __launch_bounds__(256, 2) void p3_kernel(
    const float* __restrict__ h, const float2* __restrict__ statP,
    const float* __restrict__ nwp, const float* __restrict__ nbp,
    const float2* __restrict__ f,
    const float2* __restrict__ cApJ,
    const float2* __restrict__ cA, const float2* __restrict__ cB,
    const float2* __restrict__ cC, const float2* __restrict__ cAp,
    const float* __restrict__ d_p,
    bf16* __restrict__ g, int lay) {
    __shared__ float tile[128 * 16];                // 8 KB raw h
    __shared__ float2 stat_s[128];
    const int tid = threadIdx.x;
    const int lane = tid & 63, w = tid >> 6;
    const int chl = lane & 15, sub = lane >> 4;
    const int bx = blockIdx.x, by = blockIdx.y;
    const int ch = bx * 16 + chl;
    const int chunk = by * 4 + w;

    const float* ub = h + (size_t)(by * 128) * HD + bx * 16;
#pragma unroll
    for (int r = 0; r < 2; ++r) {
        int i = r * 256 + tid;
        int tr = i >> 2, c4 = (i & 3) * 4;
        *(float4*)(tile + tr * 16 + c4) = *(const float4*)(ub + (size_t)tr * HD + c4);
    }
    if (tid < 128) {
        const float4* pp = (const float4*)(statP + (size_t)(by * 128 + tid) * 32);
        float S = 0.f, S2 = 0.f;
#pragma unroll
        for (int k = 0; k < 16; ++k) {
            float4 v = pp[k];
            S += v.x + v.z; S2 += v.y + v.w;
        }
        float m = S * (1.f / HD);
        float var = S2 * (1.f / HD) - m * m;
        stat_s[tid] = make_float2(m, rsqrtf(var + 1e-5f));
    }
    int cbase = (lay * NST + sub * 8) * HD + ch;
    float aR[8], aI[8], bR[8], bI[8], cR[8], cI[8];
#pragma unroll
    for (int j = 0; j < 8; ++j) {
        float2 t2 = cA[cbase + j * HD]; aR[j] = t2.x; aI[j] = t2.y;
        t2 = cB[cbase + j * HD];        bR[j] = t2.x; bI[j] = t2.y;
        t2 = cC[cbase + j * HD];        cR[j] = t2.x; cI[j] = t2.y;
    }
    float dch = d_p[lay * HD + ch];
    float gam = nwp[ch], bet = nbp[ch];

    // ---- carry (wave-uniform: chunk uniform per wave) ----
    const int jj = chunk & 7, ksup = chunk >> 3;
    float Sr[8], Si[8];                             // exclusive super prefix S_ksup
#pragma unroll
    for (int j = 0; j < 8; ++j) { Sr[j] = 0.f; Si[j] = 0.f; }
    if (ksup > 0) {
        const size_t CS = (size_t)NST * HD;
#pragma unroll
        for (int j = 0; j < 8; ++j) {
            float2 ap = cAp[cbase + j * HD];
            float xr = ap.x, xi = ap.y;             // ap^SUP (3 squarings)
#pragma unroll
            for (int q = 0; q < 3; ++q) { float tt = xr * xr - xi * xi; xi = 2.f * xr * xi; xr = tt; }
            const float2* fp = f + ((size_t)(sub * 8 + j)) * HD + ch;
            float s2r = 0.f, s2i = 0.f;
            for (int k = 0; k < ksup; ++k) {        // wave-uniform trip count
                float2 F = fp[(size_t)(k * 8 + 7) * CS];
                float nr = fmaf(xr, s2r, fmaf(-xi, s2i, F.x));
                float ni = fmaf(xi, s2r, fmaf( xr, s2i, F.y));
                s2r = nr; s2i = ni;
            }
            Sr[j] = s2r; Si[j] = s2i;
        }
    }
    float sr[8], si[8];
    if (chunk == 0) {
#pragma unroll
        for (int j = 0; j < 8; ++j) { sr[j] = 0.f; si[j] = 0.f; }
    } else if (jj == 0) {
#pragma unroll
        for (int j = 0; j < 8; ++j) { sr[j] = Sr[j]; si[j] = Si[j]; }
    } else {
        const float2* fw = f + ((size_t)(chunk - 1) * NST + sub * 8) * HD + ch;
        const float2* aj = cApJ + ((size_t)(lay * 7 + (jj - 1)) * NST + sub * 8) * HD + ch;
#pragma unroll
        for (int j = 0; j < 8; ++j) {
            float2 F = fw[(size_t)j * HD];
            float2 A = aj[(size_t)j * HD];
            sr[j] = fmaf(A.x, Sr[j], fmaf(-A.y, Si[j], F.x));
            si[j] = fmaf(A.x, Si[j], fmaf( A.y, Sr[j], F.y));
        }
    }
    __syncthreads();

    const float* tp = tile + (w * LC) * 16 + chl;
    bf16* gp = g + (size_t)chunk * LC * HD + ch;
#pragma unroll 4
    for (int t = 0; t < LC; ++t) {
        float2 st = stat_s[w * LC + t];
        float gr = gam * st.y;
        float off = fmaf(-st.x, gr, bet);
        float uu = fmaf(tp[t * 16], gr, off);
        float p = 0.f;
#pragma unroll
        for (int j = 0; j < 8; ++j) {
            float nr = fmaf(aR[j], sr[j], fmaf(-aI[j], si[j], bR[j] * uu));
            float ni = fmaf(aI[j], sr[j], fmaf( aR[j], si[j], bI[j] * uu));
            sr[j] = nr; si[j] = ni;
            p = fmaf(cR[j], nr, fmaf(-cI[j], ni, p));   // cC pre-scaled by 2
        }
        p += __shfl_xor(p, 16);
        p += __shfl_xor(p, 32);
        float y = fmaf(dch, uu, p);
        if (sub == 0) gp[(size_t)t * HD] = (bf16)gelu_tanh(y);
    }
}

// ---------------- MM: 64x32 tile, 512 blocks; writes next-layer LN stat partials ----
__global__ __launch_bounds__(256, 2) void mm_kernel(
    const bf16* __restrict__ A,    // g [L,H] bf16
    const bf16* __restrict__ W1,   // out_w  [H,H] (n,k) bf16
    const bf16* __restrict__ W2,   // out2_w [H,H] bf16
    const float* __restrict__ bias1, const float* __restrict__ bias2,
    float* __restrict__ Hio, float2* __restrict__ statP, int doStats) {
    const int w = threadIdx.x >> 6, lane = threadIdx.x & 63;
    const int wm = w >> 1, wn = w & 1;
    const int bm = blockIdx.x >> 4, bn = blockIdx.x & 15;
    const int mW = bm * 64 + wm * 32;
    const int nW = bn * 32 + wn * 16;
    const int lrow = lane & 15, quad = lane >> 4;

    floatx4 acc1[2] = {{0.f,0.f,0.f,0.f},{0.f,0.f,0.f,0.f}};
    floatx4 acc2[2] = {{0.f,0.f,0.f,0.f},{0.f,0.f,0.f,0.f}};
    for (int k0 = 0; k0 < HD; k0 += 32) {
        int kk = k0 + quad * 8;
        bf16x8 a0 = *(const bf16x8*)(A + (size_t)(mW + lrow) * HD + kk);
        bf16x8 a1 = *(const bf16x8*)(A + (size_t)(mW + 16 + lrow) * HD + kk);
        bf16x8 p0 = *(const bf16x8*)(W1 + (size_t)(nW + lrow) * HD + kk);
        bf16x8 q0 = *(const bf16x8*)(W2 + (size_t)(nW + lrow) * HD + kk);
        acc1[0] = __builtin_amdgcn_mfma_f32_16x16x32_bf16(a0, p0, acc1[0], 0, 0, 0);
        acc1[1] = __builtin_amdgcn_mfma_f32_16x16x32_bf16(a1, p0, acc1[1], 0, 0, 0);
        acc2[0] = __builtin_amdgcn_mfma_f32_16x16x32_bf16(a0, q0, acc2[0], 0, 0, 0);
        acc2[1] = __builtin_amdgcn_mfma_f32_16x16x32_bf16(a1, q0, acc2[1], 0, 0, 0);
    }
    int jj = nW + lrow;
    float bb1 = bias1[jj], bb2 = bias2[jj];
    float hn_[2][4];
#pragma unroll
    for (int fm = 0; fm < 2; ++fm)
#pragma unroll
        for (int r = 0; r < 4; ++r) {
            int t = mW + fm * 16 + quad * 4 + r;
            float z1 = acc1[fm][r] + bb1;
            float z2 = acc2[fm][r] + bb2;
            float v = Hio[(size_t)t * HD + jj] + z1 / (1.f + __expf(-z2));
            Hio[(size_t)t * HD + jj] = v;
            hn_[fm][r] = v;
        }
    if (doStats) {                                  // per-16-col (sum, sumsq) partials
#pragma unroll
        for (int fm = 0; fm < 2; ++fm)
#pragma unroll
            for (int r = 0; r < 4; ++r) {
                float s = hn_[fm][r], s2 = s * s;
#pragma unroll
                for (int m = 1; m <= 8; m <<= 1) {
                    s  += __shfl_xor(s, m, 64);
                    s2 += __shfl_xor(s2, m, 64);
                }
                if (lrow == 0) {
                    int t = mW + fm * 16 + quad * 4 + r;
                    statP[(size_t)t * 32 + (nW >> 4)] = make_float2(s, s2);
                }
            }
    }
}

// ---------------- decoder: out[L,3] ----------------
__global__ __launch_bounds__(192) void dec_kernel(
    const float* __restrict__ h, const float* __restrict__ w,
    const float* __restrict__ b, float* __restrict__ out) {
    int j = threadIdx.x >> 6, lane = threadIdx.x & 63;
    int t = blockIdx.x;
    const float* hp = h + (size_t)t * HD + lane * 8;
    float v[8];
    *(float4*)(v)     = *(const float4*)(hp);
    *(float4*)(v + 4) = *(const float4*)(hp + 4);
    float w8[8];
    *(float4*)(w8)     = *(const float4*)(w + j * HD + lane * 8);
    *(float4*)(w8 + 4) = *(const float4*)(w + j * HD + lane * 8 + 4);
    float s = 0.f;
#pragma unroll
    for (int e = 0; e < 8; ++e) s = fmaf(v[e], w8[e], s);
#pragma unroll
    for (int m = 32; m; m >>= 1) s += __shfl_xor(s, m, 64);
    if (lane == 0) out[t * 3 + j] = s + b[j];
}

extern "C" void kernel_launch(void* const* d_in, const int* in_sizes, int n_in,
                              void* d_out, int out_size, void* d_ws, size_t ws_size,
                              hipStream_t stream) {
    const float* x   = (const float*)d_in[0];
    const float* ew  = (const float*)d_in[1];
    const float* eb  = (const float*)d_in[2];
    const float* dw  = (const float*)d_in[3];
    const float* db  = (const float*)d_in[4];
    const float* nw  = (const float*)d_in[5];
    const float* nb  = (const float*)d_in[6];
    const float* lre = (const float*)d_in[7];
    const float* lim = (const float*)d_in[8];
    const float* bre = (const float*)d_in[9];
    const float* bim = (const float*)d_in[10];
    const float* cre = (const float*)d_in[11];
    const float* cim = (const float*)d_in[12];
    const float* dd  = (const float*)d_in[13];
    const float* ls  = (const float*)d_in[14];
    const float* ow  = (const float*)d_in[15];
    const float* ob  = (const float*)d_in[16];
    const float* o2w = (const float*)d_in[17];
    const float* o2b = (const float*)d_in[18];

    char* ws = (char*)d_ws;
    float*  h     = (float*)ws;                           // 4 MB   [L,H]
    float2* f     = (float2*)(ws + (4  << 20));           // 8.4 MB within-super prefixes
    bf16*   g     = (bf16*)(ws + (16 << 20));             // 2 MB   [L,H] bf16
    bf16*   wb    = (bf16*)(ws + (18 << 20));             // 4 MB   bf16 weights
    float2* cA    = (float2*)(ws + (22 << 20));           // 512 KB [4][NST][HD]
    float2* cB    = (float2*)(ws + (22 << 20) + (512 << 10));
    float2* cC    = (float2*)(ws + (23 << 20));
    float2* cAp   = (float2*)(ws + (23 << 20) + (512 << 10));
    float2* statP = (float2*)(ws + (24 << 20));           // 512 KB [L][32] (sum,sumsq)
    float2* cApJ  = (float2*)(ws + (25 << 20));           // 3.5 MB [4][7][NST][HD]

    setup_kernel<<<5376, 256, 0, stream>>>(x, ew, eb, ow, o2w,
                                           lre, lim, bre, bim, cre, cim, ls,
                                           h, wb, cA, cB, cC, cAp, cApJ, statP);
    for (int lay = 0; lay < 4; ++lay) {
        int oH = lay * HD;
        p1_kernel<<<dim3(HD / 16, NSUP), 512, 0, stream>>>(
            h, statP, nw + oH, nb + oH, cA, cB, cAp, f, lay);
        p3_kernel<<<dim3(HD / 16, NCHK / 4), 256, 0, stream>>>(
            h, statP, nw + oH, nb + oH, f, cApJ, cA, cB, cC, cAp, dd, g, lay);
        mm_kernel<<<512, 256, 0, stream>>>(
            g, wb + lay * HH, wb + 4 * HH + lay * HH, ob + oH, o2b + oH, h,
            statP, lay < 3 ? 1 : 0);
    }
    dec_kernel<<<LSEQ, 192, 0, stream>>>(h, dw, db, (float*)d_out);
}

// Round 10
// 312.766 us; speedup vs baseline: 1.0611x; 1.0611x over previous
//
#include <hip/hip_runtime.h>
#include <hip/hip_bf16.h>
#include <math.h>

#define LSEQ 2048
#define HD   512
#define NST  32
#define LC   32
#define NCHK 64   /* LSEQ/LC */
#define HH   (HD * HD)
#define NTHR 256

typedef __bf16 bf16;
typedef __bf16 bf16x8 __attribute__((ext_vector_type(8)));
typedef float  floatx4 __attribute__((ext_vector_type(4)));

__device__ __forceinline__ float gelu_tanh(float x) {
    float z = 0.7978845608028654f * (x + 0.044715f * x * x * x);
    float e = __expf(2.f * z);
    float th = 1.f - 2.f / (e + 1.f);   // tanh(z), saturates cleanly
    return 0.5f * x * (1.f + th);
}

__device__ __forceinline__ void make_ab(float lre, float lim, float step,
                                        float br0, float bi0,
                                        float& ar, float& ai, float& br, float& bi) {
    float s2 = 0.5f * step;
    float dr = 1.f - s2 * lre, di = -s2 * lim;      // 1 - (dt/2)Lam
    float inv = 1.f / (dr * dr + di * di);
    float blr = dr * inv, bli = -di * inv;          // BL = 1/(dr+i*di)
    float nr = 1.f + s2 * lre, ni = s2 * lim;       // 1 + (dt/2)Lam
    ar = blr * nr - bli * ni;
    ai = blr * ni + bli * nr;
    float tr = step * br0, ti = step * bi0;         // dt * B
    br = blr * tr - bli * ti;
    bi = blr * ti + bli * tr;
}

// ---------------- setup: encoder(+layer-0 stat partials) + weight cvt + prep --------
// blocks 0..4095: encoder; 4096..5119: cvt; 5120..5375: prep
__global__ __launch_bounds__(256) void setup_kernel(
    const float* __restrict__ x,   const float* __restrict__ ew,
    const float* __restrict__ eb,  const float* __restrict__ ow,
    const float* __restrict__ o2w,
    const float* __restrict__ lre, const float* __restrict__ lim,
    const float* __restrict__ bre, const float* __restrict__ bim,
    const float* __restrict__ cre, const float* __restrict__ cim,
    const float* __restrict__ ls,
    float* __restrict__ h, bf16* __restrict__ wb,
    float2* __restrict__ cA, float2* __restrict__ cB,
    float2* __restrict__ cC, float2* __restrict__ cAp,
    float2* __restrict__ statP) {
    int bid = blockIdx.x, tid = threadIdx.x;
    if (bid < 4096) {                               // encoder: [L,4] @ [4,H]^T
        int idx = bid * 256 + tid;
        int t = idx >> 9, col = idx & (HD - 1);
        float4 xv = *(const float4*)(x + t * 4);
        float4 wv = *(const float4*)(ew + col * 4);
        float acc = eb[col];
        acc = fmaf(xv.x, wv.x, acc); acc = fmaf(xv.y, wv.y, acc);
        acc = fmaf(xv.z, wv.z, acc); acc = fmaf(xv.w, wv.w, acc);
        h[idx] = acc;
        // LN stat partials for layer 0: per-16-col (sum, sumsq)
        float s = acc, s2 = acc * acc;
#pragma unroll
        for (int m = 1; m <= 8; m <<= 1) {
            s  += __shfl_xor(s, m, 64);
            s2 += __shfl_xor(s2, m, 64);
        }
        if ((tid & 15) == 0) statP[(size_t)t * 32 + (col >> 4)] = make_float2(s, s2);
    } else if (bid < 5120) {                        // f32 -> bf16 weights
        int b2 = bid - 4096;
        const float* src = (b2 >= 512) ? o2w : ow;
        bf16* dst = wb + (b2 >= 512 ? 4 * HH : 0);
        int i = ((b2 & 511) * 256 + tid) * 8;
        float4 a = *(const float4*)(src + i);
        float4 b = *(const float4*)(src + i + 4);
        bf16x8 o;
        o[0] = (bf16)a.x; o[1] = (bf16)a.y; o[2] = (bf16)a.z; o[3] = (bf16)a.w;
        o[4] = (bf16)b.x; o[5] = (bf16)b.y; o[6] = (bf16)b.z; o[7] = (bf16)b.w;
        *(bf16x8*)(dst + i) = o;
    } else {                                        // coefficient prep (65536 threads)
        int tg = (bid - 5120) * 256 + tid;
        int lay = tg >> 14, rem = tg & 16383;
        int ch = rem >> 5, n = rem & 31;
        float step = __expf(ls[lay * HD + ch]);
        float ar, ai, br, bi;
        make_ab(lre[tg], lim[tg], step, bre[tg], bim[tg], ar, ai, br, bi);
        float xr = ar, xi = ai;                     // Abar^LC (5 squarings)
#pragma unroll
        for (int q = 0; q < 5; ++q) { float tt = xr * xr - xi * xi; xi = 2.f * xr * xi; xr = tt; }
        int dst = (lay * NST + n) * HD + ch;
        cA[dst]  = make_float2(ar, ai);
        cB[dst]  = make_float2(br, bi);
        cC[dst]  = make_float2(2.f * cre[tg], 2.f * cim[tg]);
        cAp[dst] = make_float2(xr, xi);
    }
}

// ---------------- stats + tile loader: h -> LDS with inline LayerNorm ----------------
__device__ __forceinline__ void stats_and_tile(
    float* tile, float2* stat_s,
    const float* __restrict__ h, const float2* __restrict__ statP,
    const float* __restrict__ nwp, const float* __restrict__ nbp,
    int bx, int by, int tid) {
    // per-row LN stats from 32 per-16-col partials (E[x^2] - m^2 form)
    if (tid < 128) {
        const float4* pp = (const float4*)(statP + (size_t)(by * 128 + tid) * 32);
        float S = 0.f, S2 = 0.f;
#pragma unroll
        for (int k = 0; k < 16; ++k) {
            float4 v = pp[k];
            S += v.x + v.z; S2 += v.y + v.w;
        }
        float m = S * (1.f / HD);
        float var = S2 * (1.f / HD) - m * m;
        stat_s[tid] = make_float2(m, rsqrtf(var + 1e-5f));
    }
    __syncthreads();
    const float* ub = h + (size_t)(by * 4 * LC) * HD + bx * 16;
    const float* wp = nwp + bx * 16;
    const float* bp = nbp + bx * 16;
#pragma unroll
    for (int r = 0; r < 2; ++r) {                   // 512 float4 loads
        int i = r * NTHR + tid;
        int tr = i >> 2, c4 = (i & 3) * 4;
        float4 hv = *(const float4*)(ub + (size_t)tr * HD + c4);
        float2 s2 = stat_s[tr];
        float4 gv = *(const float4*)(wp + c4);
        float4 bv = *(const float4*)(bp + c4);
        float4 o;
        o.x = (hv.x - s2.x) * s2.y * gv.x + bv.x;
        o.y = (hv.y - s2.x) * s2.y * gv.y + bv.y;
        o.z = (hv.z - s2.x) * s2.y * gv.z + bv.z;
        o.w = (hv.w - s2.x) * s2.y * gv.w + bv.w;
        *(float4*)(tile + tr * 16 + c4) = o;
    }
}

// ---------------- P1: per-chunk local final states ----------------
// grid (32, 16); block: 16 ch x 4 chunks (one per wave); lane: 16 ch x 4 sub(8 states)
__global__ __launch_bounds__(256, 2) void p1_kernel(
    const float* __restrict__ h, const float2* __restrict__ statP,
    const float* __restrict__ nwp, const float* __restrict__ nbp,
    const float2* __restrict__ cA, const float2* __restrict__ cB,
    float2* __restrict__ f, int lay) {
    __shared__ float tile[4 * LC * 16];             // 8 KB
    __shared__ float2 stat_s[128];
    int tid = threadIdx.x;
    int lane = tid & 63, w = tid >> 6;
    int chl = lane & 15, sub = lane >> 4;
    int bx = blockIdx.x, by = blockIdx.y;
    int ch = bx * 16 + chl;
    int chunk = by * 4 + w;
    stats_and_tile(tile, stat_s, h, statP, nwp, nbp, bx, by, tid);
    int cbase = (lay * NST + sub * 8) * HD + ch;
    float aR[8], aI[8], bR[8], bI[8];
#pragma unroll
    for (int j = 0; j < 8; ++j) {
        float2 t = cA[cbase + j * HD]; aR[j] = t.x; aI[j] = t.y;
        t = cB[cbase + j * HD];        bR[j] = t.x; bI[j] = t.y;
    }
    float sr[8], si[8];
#pragma unroll
    for (int j = 0; j < 8; ++j) { sr[j] = 0.f; si[j] = 0.f; }
    __syncthreads();
    const float* tp = tile + (w * LC) * 16 + chl;
#pragma unroll 4
    for (int t = 0; t < LC; ++t) {
        float uu = tp[t * 16];
#pragma unroll
        for (int j = 0; j < 8; ++j) {
            float nr = fmaf(aR[j], sr[j], fmaf(-aI[j], si[j], bR[j] * uu));
            float ni = fmaf(aI[j], sr[j], fmaf( aR[j], si[j], bI[j] * uu));
            sr[j] = nr; si[j] = ni;
        }
    }
    float2* fp = f + (size_t)(chunk * NST + sub * 8) * HD + ch;
#pragma unroll
    for (int j = 0; j < 8; ++j) fp[(size_t)j * HD] = make_float2(sr[j], si[j]);
}

// ---------------- P2: single-pass cross-chunk scan, 8-deep double-buffered ----------
__global__ __launch_bounds__(256) void p2_kernel(
    float2* __restrict__ f, const float2* __restrict__ cAp, int lay) {
    int tg = blockIdx.x * 256 + threadIdx.x;        // 16384 = 32*512 chains
    int ch = tg & 511, n = tg >> 9;
    float2 ap = cAp[(lay * NST + n) * HD + ch];
    float2* fp = f + (size_t)n * HD + ch;
    const size_t CS = (size_t)NST * HD;             // float2 stride per chunk
    float2 cur[8], nxt[8];
#pragma unroll
    for (int k = 0; k < 8; ++k) cur[k] = fp[(size_t)k * CS];
    float sr = 0.f, si = 0.f;
#pragma unroll
    for (int b = 0; b < 8; ++b) {
        if (b < 7) {
#pragma unroll
            for (int k = 0; k < 8; ++k) nxt[k] = fp[(size_t)(b * 8 + 8 + k) * CS];
        }
#pragma unroll
        for (int k = 0; k < 8; ++k) {
            float nr = fmaf(ap.x, sr, fmaf(-ap.y, si, cur[k].x));
            float ni = fmaf(ap.y, sr, fmaf( ap.x, si, cur[k].y));
            sr = nr; si = ni;
            fp[(size_t)(b * 8 + k) * CS] = make_float2(sr, si);
        }
#pragma unroll
        for (int k = 0; k < 8; ++k) cur[k] = nxt[k];
    }
}

// ---------------- P3: replay with carried init, emit gelu(y) as bf16 ----------------
__global__ __launch_bounds__(256, 2) void p3_kernel(
    const float* __restrict__ h, const float2* __restrict__ statP,
    const float* __restrict__ nwp, const float* __restrict__ nbp,
    const float2* __restrict__ f,
    const float2* __restrict__ cA, const float2* __restrict__ cB,
    const float2* __restrict__ cC, const float* __restrict__ d_p,
    bf16* __restrict__ g, int lay) {
    __shared__ float tile[4 * LC * 16];             // 8 KB
    __shared__ float2 stat_s[128];
    int tid = threadIdx.x;
    int lane = tid & 63, w = tid >> 6;
    int chl = lane & 15, sub = lane >> 4;
    int bx = blockIdx.x, by = blockIdx.y;
    int ch = bx * 16 + chl;
    int chunk = by * 4 + w;
    stats_and_tile(tile, stat_s, h, statP, nwp, nbp, bx, by, tid);
    int cbase = (lay * NST + sub * 8) * HD + ch;
    float aR[8], aI[8], bR[8], bI[8], cR[8], cI[8];
#pragma unroll
    for (int j = 0; j < 8; ++j) {
        float2 t = cA[cbase + j * HD]; aR[j] = t.x; aI[j] = t.y;
        t = cB[cbase + j * HD];        bR[j] = t.x; bI[j] = t.y;
        t = cC[cbase + j * HD];        cR[j] = t.x; cI[j] = t.y;
    }
    float dch = d_p[lay * HD + ch];
    float sr[8], si[8];
    if (chunk > 0) {
        const float2* ip = f + (size_t)((chunk - 1) * NST + sub * 8) * HD + ch;
#pragma unroll
        for (int j = 0; j < 8; ++j) { float2 v = ip[(size_t)j * HD]; sr[j] = v.x; si[j] = v.y; }
    } else {
#pragma unroll
        for (int j = 0; j < 8; ++j) { sr[j] = 0.f; si[j] = 0.f; }
    }
    __syncthreads();
    const float* tp = tile + (w * LC) * 16 + chl;
    bf16* gp = g + (size_t)chunk * LC * HD + ch;
#pragma unroll 4
    for (int t = 0; t < LC; ++t) {
        float uu = tp[t * 16];
        float p = 0.f;
#pragma unroll
        for (int j = 0; j < 8; ++j) {
            float nr = fmaf(aR[j], sr[j], fmaf(-aI[j], si[j], bR[j] * uu));
            float ni = fmaf(aI[j], sr[j], fmaf( aR[j], si[j], bI[j] * uu));
            sr[j] = nr; si[j] = ni;
            p = fmaf(cR[j], nr, fmaf(-cI[j], ni, p));   // cC pre-scaled by 2
        }
        p += __shfl_xor(p, 16);
        p += __shfl_xor(p, 32);
        float y = fmaf(dch, uu, p);
        if (sub == 0) gp[(size_t)t * HD] = (bf16)gelu_tanh(y);
    }
}

// ---------------- MM: 64x32 tile, 512 blocks, XCD-chunked swizzle + reg prefetch ----
// vb = (bid&7)*64 + bid>>3: each XCD's 64 blocks get a contiguous bm range ->
// A-slice (256 KB) + full W (1 MB) L2-resident per XCD instead of L3 re-fetch.
__global__ __launch_bounds__(256, 2) void mm_kernel(
    const bf16* __restrict__ A,    // g [L,H] bf16
    const bf16* __restrict__ W1,   // out_w  [H,H] (n,k) bf16
    const bf16* __restrict__ W2,   // out2_w [H,H] bf16
    const float* __restrict__ bias1, const float* __restrict__ bias2,
    float* __restrict__ Hio, float2* __restrict__ statP, int doStats) {
    const int w = threadIdx.x >> 6, lane = threadIdx.x & 63;
    const int wm = w >> 1, wn = w & 1;
    const int bid = blockIdx.x;
    const int vb = (bid & 7) * 64 + (bid >> 3);     // XCD-chunked remap (bijective)
    const int bm = vb >> 4, bn = vb & 15;
    const int mW = bm * 64 + wm * 32;
    const int nW = bn * 32 + wn * 16;
    const int lrow = lane & 15, quad = lane >> 4;

    const bf16* pA0 = A  + (size_t)(mW + lrow) * HD + quad * 8;
    const bf16* pA1 = A  + (size_t)(mW + 16 + lrow) * HD + quad * 8;
    const bf16* pW1 = W1 + (size_t)(nW + lrow) * HD + quad * 8;
    const bf16* pW2 = W2 + (size_t)(nW + lrow) * HD + quad * 8;

    floatx4 acc1[2] = {{0.f,0.f,0.f,0.f},{0.f,0.f,0.f,0.f}};
    floatx4 acc2[2] = {{0.f,0.f,0.f,0.f},{0.f,0.f,0.f,0.f}};
    bf16x8 a0 = *(const bf16x8*)(pA0);
    bf16x8 a1 = *(const bf16x8*)(pA1);
    bf16x8 p0 = *(const bf16x8*)(pW1);
    bf16x8 q0 = *(const bf16x8*)(pW2);
#pragma unroll
    for (int k0 = 0; k0 < HD; k0 += 32) {
        bf16x8 na0 = a0, na1 = a1, np0 = p0, nq0 = q0;   // safe rotate (no undef)
        if (k0 + 32 < HD) {                         // prefetch next K-tile
            na0 = *(const bf16x8*)(pA0 + k0 + 32);
            na1 = *(const bf16x8*)(pA1 + k0 + 32);
            np0 = *(const bf16x8*)(pW1 + k0 + 32);
            nq0 = *(const bf16x8*)(pW2 + k0 + 32);
        }
        acc1[0] = __builtin_amdgcn_mfma_f32_16x16x32_bf16(a0, p0, acc1[0], 0, 0, 0);
        acc1[1] = __builtin_amdgcn_mfma_f32_16x16x32_bf16(a1, p0, acc1[1], 0, 0, 0);
        acc2[0] = __builtin_amdgcn_mfma_f32_16x16x32_bf16(a0, q0, acc2[0], 0, 0, 0);
        acc2[1] = __builtin_amdgcn_mfma_f32_16x16x32_bf16(a1, q0, acc2[1], 0, 0, 0);
        a0 = na0; a1 = na1; p0 = np0; q0 = nq0;
    }
    int jj = nW + lrow;
    float bb1 = bias1[jj], bb2 = bias2[jj];
    float hn_[2][4];
#pragma unroll
    for (int fm = 0; fm < 2; ++fm)
#pragma unroll
        for (int r = 0; r < 4; ++r) {
            int t = mW + fm * 16 + quad * 4 + r;
            float z1 = acc1[fm][r] + bb1;
            float z2 = acc2[fm][r] + bb2;
            float v = Hio[(size_t)t * HD + jj] + z1 / (1.f + __expf(-z2));
            Hio[(size_t)t * HD + jj] = v;
            hn_[fm][r] = v;
        }
    if (doStats) {                                  // per-16-col (sum, sumsq) partials
#pragma unroll
        for (int fm = 0; fm < 2; ++fm)
#pragma unroll
            for (int r = 0; r < 4; ++r) {
                float s = hn_[fm][r], s2 = s * s;
#pragma unroll
                for (int m = 1; m <= 8; m <<= 1) {
                    s  += __shfl_xor(s, m, 64);
                    s2 += __shfl_xor(s2, m, 64);
                }
                if (lrow == 0) {
                    int t = mW + fm * 16 + quad * 4 + r;
                    statP[(size_t)t * 32 + (nW >> 4)] = make_float2(s, s2);
                }
            }
    }
}

// ---------------- decoder: 512 blocks x 4 waves, wave per row, 3 outputs ------------
__global__ __launch_bounds__(256) void dec_kernel(
    const float* __restrict__ h, const float* __restrict__ w,
    const float* __restrict__ b, float* __restrict__ out) {
    int wv = threadIdx.x >> 6, lane = threadIdx.x & 63;
    int t = blockIdx.x * 4 + wv;
    const float* hp = h + (size_t)t * HD + lane * 8;
    float v[8];
    *(float4*)(v)     = *(const float4*)(hp);
    *(float4*)(v + 4) = *(const float4*)(hp + 4);
#pragma unroll
    for (int j = 0; j < 3; ++j) {
        float w8[8];
        *(float4*)(w8)     = *(const float4*)(w + j * HD + lane * 8);
        *(float4*)(w8 + 4) = *(const float4*)(w + j * HD + lane * 8 + 4);
        float s = 0.f;
#pragma unroll
        for (int e = 0; e < 8; ++e) s = fmaf(v[e], w8[e], s);
#pragma unroll
        for (int m = 32; m; m >>= 1) s += __shfl_xor(s, m, 64);
        if (lane == 0) out[t * 3 + j] = s + b[j];
    }
}

extern "C" void kernel_launch(void* const* d_in, const int* in_sizes, int n_in,
                              void* d_out, int out_size, void* d_ws, size_t ws_size,
                              hipStream_t stream) {
    const float* x   = (const float*)d_in[0];
    const float* ew  = (const float*)d_in[1];
    const float* eb  = (const float*)d_in[2];
    const float* dw  = (const float*)d_in[3];
    const float* db  = (const float*)d_in[4];
    const float* nw  = (const float*)d_in[5];
    const float* nb  = (const float*)d_in[6];
    const float* lre = (const float*)d_in[7];
    const float* lim = (const float*)d_in[8];
    const float* bre = (const float*)d_in[9];
    const float* bim = (const float*)d_in[10];
    const float* cre = (const float*)d_in[11];
    const float* cim = (const float*)d_in[12];
    const float* dd  = (const float*)d_in[13];
    const float* ls  = (const float*)d_in[14];
    const float* ow  = (const float*)d_in[15];
    const float* ob  = (const float*)d_in[16];
    const float* o2w = (const float*)d_in[17];
    const float* o2b = (const float*)d_in[18];

    char* ws = (char*)d_ws;
    float*  h     = (float*)ws;                           // 4 MB   [L,H]
    float2* f     = (float2*)(ws + (4  << 20));           // 8.4 MB [NCHK][NST][HD]
    bf16*   g     = (bf16*)(ws + (16 << 20));             // 2 MB   [L,H] bf16
    bf16*   wb    = (bf16*)(ws + (18 << 20));             // 4 MB   bf16 weights
    float2* cA    = (float2*)(ws + (22 << 20));           // 512 KB [4][NST][HD]
    float2* cB    = (float2*)(ws + (22 << 20) + (512 << 10));
    float2* cC    = (float2*)(ws + (23 << 20));
    float2* cAp   = (float2*)(ws + (23 << 20) + (512 << 10));
    float2* statP = (float2*)(ws + (24 << 20));           // 512 KB [L][32] (sum,sumsq)

    setup_kernel<<<5376, 256, 0, stream>>>(x, ew, eb, ow, o2w,
                                           lre, lim, bre, bim, cre, cim, ls,
                                           h, wb, cA, cB, cC, cAp, statP);
    for (int lay = 0; lay < 4; ++lay) {
        int oH = lay * HD;
        p1_kernel<<<dim3(HD / 16, NCHK / 4), 256, 0, stream>>>(
            h, statP, nw + oH, nb + oH, cA, cB, f, lay);
        p2_kernel<<<64, 256, 0, stream>>>(f, cAp, lay);
        p3_kernel<<<dim3(HD / 16, NCHK / 4), 256, 0, stream>>>(
            h, statP, nw + oH, nb + oH, f, cA, cB, cC, dd, g, lay);
        mm_kernel<<<512, 256, 0, stream>>>(
            g, wb + lay * HH, wb + 4 * HH + lay * HH, ob + oH, o2b + oH, h,
            statP, lay < 3 ? 1 : 0);
    }
    dec_kernel<<<LSEQ / 4, 256, 0, stream>>>(h, dw, db, (float*)d_out);
}

// Round 11
// 305.220 us; speedup vs baseline: 1.0874x; 1.0247x over previous
//
#include <hip/hip_runtime.h>
#include <hip/hip_bf16.h>
#include <math.h>

#define LSEQ 2048
#define HD   512
#define NST  32
#define LC   32
#define NCHK 64   /* LSEQ/LC */
#define HH   (HD * HD)
#define NTHR 256

typedef __bf16 bf16;
typedef __bf16 bf16x8 __attribute__((ext_vector_type(8)));
typedef float  floatx4 __attribute__((ext_vector_type(4)));

__device__ __forceinline__ float gelu_tanh(float x) {
    float z = 0.7978845608028654f * (x + 0.044715f * x * x * x);
    float e = __expf(2.f * z);
    float th = 1.f - 2.f / (e + 1.f);   // tanh(z), saturates cleanly
    return 0.5f * x * (1.f + th);
}

__device__ __forceinline__ void make_ab(float lre, float lim, float step,
                                        float br0, float bi0,
                                        float& ar, float& ai, float& br, float& bi) {
    float s2 = 0.5f * step;
    float dr = 1.f - s2 * lre, di = -s2 * lim;      // 1 - (dt/2)Lam
    float inv = 1.f / (dr * dr + di * di);
    float blr = dr * inv, bli = -di * inv;          // BL = 1/(dr+i*di)
    float nr = 1.f + s2 * lre, ni = s2 * lim;       // 1 + (dt/2)Lam
    ar = blr * nr - bli * ni;
    ai = blr * ni + bli * nr;
    float tr = step * br0, ti = step * bi0;         // dt * B
    br = blr * tr - bli * ti;
    bi = blr * ti + bli * tr;
}

// ---------------- setup: encoder(+layer-0 stat partials) + weight cvt + prep --------
// blocks 0..4095: encoder; 4096..5119: cvt; 5120..5375: prep
__global__ __launch_bounds__(256) void setup_kernel(
    const float* __restrict__ x,   const float* __restrict__ ew,
    const float* __restrict__ eb,  const float* __restrict__ ow,
    const float* __restrict__ o2w,
    const float* __restrict__ lre, const float* __restrict__ lim,
    const float* __restrict__ bre, const float* __restrict__ bim,
    const float* __restrict__ cre, const float* __restrict__ cim,
    const float* __restrict__ ls,
    float* __restrict__ h, bf16* __restrict__ wb,
    float2* __restrict__ cA, float2* __restrict__ cB,
    float2* __restrict__ cC, float2* __restrict__ cAp,
    float2* __restrict__ statP) {
    int bid = blockIdx.x, tid = threadIdx.x;
    if (bid < 4096) {                               // encoder: [L,4] @ [4,H]^T
        int idx = bid * 256 + tid;
        int t = idx >> 9, col = idx & (HD - 1);
        float4 xv = *(const float4*)(x + t * 4);
        float4 wv = *(const float4*)(ew + col * 4);
        float acc = eb[col];
        acc = fmaf(xv.x, wv.x, acc); acc = fmaf(xv.y, wv.y, acc);
        acc = fmaf(xv.z, wv.z, acc); acc = fmaf(xv.w, wv.w, acc);
        h[idx] = acc;
        // LN stat partials for layer 0: per-16-col (sum, sumsq)
        float s = acc, s2 = acc * acc;
#pragma unroll
        for (int m = 1; m <= 8; m <<= 1) {
            s  += __shfl_xor(s, m, 64);
            s2 += __shfl_xor(s2, m, 64);
        }
        if ((tid & 15) == 0) statP[(size_t)t * 32 + (col >> 4)] = make_float2(s, s2);
    } else if (bid < 5120) {                        // f32 -> bf16 weights
        int b2 = bid - 4096;
        const float* src = (b2 >= 512) ? o2w : ow;
        bf16* dst = wb + (b2 >= 512 ? 4 * HH : 0);
        int i = ((b2 & 511) * 256 + tid) * 8;
        float4 a = *(const float4*)(src + i);
        float4 b = *(const float4*)(src + i + 4);
        bf16x8 o;
        o[0] = (bf16)a.x; o[1] = (bf16)a.y; o[2] = (bf16)a.z; o[3] = (bf16)a.w;
        o[4] = (bf16)b.x; o[5] = (bf16)b.y; o[6] = (bf16)b.z; o[7] = (bf16)b.w;
        *(bf16x8*)(dst + i) = o;
    } else {                                        // coefficient prep (65536 threads)
        int tg = (bid - 5120) * 256 + tid;
        int lay = tg >> 14, rem = tg & 16383;
        int ch = rem >> 5, n = rem & 31;
        float step = __expf(ls[lay * HD + ch]);
        float ar, ai, br, bi;
        make_ab(lre[tg], lim[tg], step, bre[tg], bim[tg], ar, ai, br, bi);
        float xr = ar, xi = ai;                     // Abar^LC (5 squarings)
#pragma unroll
        for (int q = 0; q < 5; ++q) { float tt = xr * xr - xi * xi; xi = 2.f * xr * xi; xr = tt; }
        int dst = (lay * NST + n) * HD + ch;
        cA[dst]  = make_float2(ar, ai);
        cB[dst]  = make_float2(br, bi);
        cC[dst]  = make_float2(2.f * cre[tg], 2.f * cim[tg]);
        cAp[dst] = make_float2(xr, xi);
    }
}

// ---------------- stats + tile loader: h -> LDS with inline LayerNorm ----------------
__device__ __forceinline__ void stats_and_tile(
    float* tile, float2* stat_s,
    const float* __restrict__ h, const float2* __restrict__ statP,
    const float* __restrict__ nwp, const float* __restrict__ nbp,
    int bx, int by, int tid) {
    // per-row LN stats from 32 per-16-col partials (E[x^2] - m^2 form)
    if (tid < 128) {
        const float4* pp = (const float4*)(statP + (size_t)(by * 128 + tid) * 32);
        float S = 0.f, S2 = 0.f;
#pragma unroll
        for (int k = 0; k < 16; ++k) {
            float4 v = pp[k];
            S += v.x + v.z; S2 += v.y + v.w;
        }
        float m = S * (1.f / HD);
        float var = S2 * (1.f / HD) - m * m;
        stat_s[tid] = make_float2(m, rsqrtf(var + 1e-5f));
    }
    __syncthreads();
    const float* ub = h + (size_t)(by * 4 * LC) * HD + bx * 16;
    const float* wp = nwp + bx * 16;
    const float* bp = nbp + bx * 16;
#pragma unroll
    for (int r = 0; r < 2; ++r) {                   // 512 float4 loads
        int i = r * NTHR + tid;
        int tr = i >> 2, c4 = (i & 3) * 4;
        float4 hv = *(const float4*)(ub + (size_t)tr * HD + c4);
        float2 s2 = stat_s[tr];
        float4 gv = *(const float4*)(wp + c4);
        float4 bv = *(const float4*)(bp + c4);
        float4 o;
        o.x = (hv.x - s2.x) * s2.y * gv.x + bv.x;
        o.y = (hv.y - s2.x) * s2.y * gv.y + bv.y;
        o.z = (hv.z - s2.x) * s2.y * gv.z + bv.z;
        o.w = (hv.w - s2.x) * s2.y * gv.w + bv.w;
        *(float4*)(tile + tr * 16 + c4) = o;
    }
}

// ---------------- P1: per-chunk local final states ----------------
// grid (32, 16); block: 16 ch x 4 chunks (one per wave); lane: 16 ch x 4 sub(8 states)
__global__ __launch_bounds__(256, 2) void p1_kernel(
    const float* __restrict__ h, const float2* __restrict__ statP,
    const float* __restrict__ nwp, const float* __restrict__ nbp,
    const float2* __restrict__ cA, const float2* __restrict__ cB,
    float2* __restrict__ f, int lay) {
    __shared__ float tile[4 * LC * 16];             // 8 KB
    __shared__ float2 stat_s[128];
    int tid = threadIdx.x;
    int lane = tid & 63, w = tid >> 6;
    int chl = lane & 15, sub = lane >> 4;
    int bx = blockIdx.x, by = blockIdx.y;
    int ch = bx * 16 + chl;
    int chunk = by * 4 + w;
    stats_and_tile(tile, stat_s, h, statP, nwp, nbp, bx, by, tid);
    int cbase = (lay * NST + sub * 8) * HD + ch;
    float aR[8], aI[8], bR[8], bI[8];
#pragma unroll
    for (int j = 0; j < 8; ++j) {
        float2 t = cA[cbase + j * HD]; aR[j] = t.x; aI[j] = t.y;
        t = cB[cbase + j * HD];        bR[j] = t.x; bI[j] = t.y;
    }
    float sr[8], si[8];
#pragma unroll
    for (int j = 0; j < 8; ++j) { sr[j] = 0.f; si[j] = 0.f; }
    __syncthreads();
    const float* tp = tile + (w * LC) * 16 + chl;
#pragma unroll 4
    for (int t = 0; t < LC; ++t) {
        float uu = tp[t * 16];
#pragma unroll
        for (int j = 0; j < 8; ++j) {
            float nr = fmaf(aR[j], sr[j], fmaf(-aI[j], si[j], bR[j] * uu));
            float ni = fmaf(aI[j], sr[j], fmaf( aR[j], si[j], bI[j] * uu));
            sr[j] = nr; si[j] = ni;
        }
    }
    float2* fp = f + (size_t)(chunk * NST + sub * 8) * HD + ch;
#pragma unroll
    for (int j = 0; j < 8; ++j) fp[(size_t)j * HD] = make_float2(sr[j], si[j]);
}

// ---------------- P2: single-pass cross-chunk scan, 8-deep double-buffered ----------
__global__ __launch_bounds__(256) void p2_kernel(
    float2* __restrict__ f, const float2* __restrict__ cAp, int lay) {
    int tg = blockIdx.x * 256 + threadIdx.x;        // 16384 = 32*512 chains
    int ch = tg & 511, n = tg >> 9;
    float2 ap = cAp[(lay * NST + n) * HD + ch];
    float2* fp = f + (size_t)n * HD + ch;
    const size_t CS = (size_t)NST * HD;             // float2 stride per chunk
    float2 cur[8], nxt[8];
#pragma unroll
    for (int k = 0; k < 8; ++k) cur[k] = fp[(size_t)k * CS];
    float sr = 0.f, si = 0.f;
#pragma unroll
    for (int b = 0; b < 8; ++b) {
        if (b < 7) {
#pragma unroll
            for (int k = 0; k < 8; ++k) nxt[k] = fp[(size_t)(b * 8 + 8 + k) * CS];
        }
#pragma unroll
        for (int k = 0; k < 8; ++k) {
            float nr = fmaf(ap.x, sr, fmaf(-ap.y, si, cur[k].x));
            float ni = fmaf(ap.y, sr, fmaf( ap.x, si, cur[k].y));
            sr = nr; si = ni;
            fp[(size_t)(b * 8 + k) * CS] = make_float2(sr, si);
        }
#pragma unroll
        for (int k = 0; k < 8; ++k) cur[k] = nxt[k];
    }
}

// ---------------- P3: replay with carried init, emit gelu(y) as bf16 ----------------
__global__ __launch_bounds__(256, 2) void p3_kernel(
    const float* __restrict__ h, const float2* __restrict__ statP,
    const float* __restrict__ nwp, const float* __restrict__ nbp,
    const float2* __restrict__ f,
    const float2* __restrict__ cA, const float2* __restrict__ cB,
    const float2* __restrict__ cC, const float* __restrict__ d_p,
    bf16* __restrict__ g, int lay) {
    __shared__ float tile[4 * LC * 16];             // 8 KB
    __shared__ float2 stat_s[128];
    int tid = threadIdx.x;
    int lane = tid & 63, w = tid >> 6;
    int chl = lane & 15, sub = lane >> 4;
    int bx = blockIdx.x, by = blockIdx.y;
    int ch = bx * 16 + chl;
    int chunk = by * 4 + w;
    stats_and_tile(tile, stat_s, h, statP, nwp, nbp, bx, by, tid);
    int cbase = (lay * NST + sub * 8) * HD + ch;
    float aR[8], aI[8], bR[8], bI[8], cR[8], cI[8];
#pragma unroll
    for (int j = 0; j < 8; ++j) {
        float2 t = cA[cbase + j * HD]; aR[j] = t.x; aI[j] = t.y;
        t = cB[cbase + j * HD];        bR[j] = t.x; bI[j] = t.y;
        t = cC[cbase + j * HD];        cR[j] = t.x; cI[j] = t.y;
    }
    float dch = d_p[lay * HD + ch];
    float sr[8], si[8];
    if (chunk > 0) {
        const float2* ip = f + (size_t)((chunk - 1) * NST + sub * 8) * HD + ch;
#pragma unroll
        for (int j = 0; j < 8; ++j) { float2 v = ip[(size_t)j * HD]; sr[j] = v.x; si[j] = v.y; }
    } else {
#pragma unroll
        for (int j = 0; j < 8; ++j) { sr[j] = 0.f; si[j] = 0.f; }
    }
    __syncthreads();
    const float* tp = tile + (w * LC) * 16 + chl;
    bf16* gp = g + (size_t)chunk * LC * HD + ch;
#pragma unroll 4
    for (int t = 0; t < LC; ++t) {
        float uu = tp[t * 16];
        float p = 0.f;
#pragma unroll
        for (int j = 0; j < 8; ++j) {
            float nr = fmaf(aR[j], sr[j], fmaf(-aI[j], si[j], bR[j] * uu));
            float ni = fmaf(aI[j], sr[j], fmaf( aR[j], si[j], bI[j] * uu));
            sr[j] = nr; si[j] = ni;
            p = fmaf(cR[j], nr, fmaf(-cI[j], ni, p));   // cC pre-scaled by 2
        }
        p += __shfl_xor(p, 16);
        p += __shfl_xor(p, 32);
        float y = fmaf(dch, uu, p);
        if (sub == 0) gp[(size_t)t * HD] = (bf16)gelu_tanh(y);
    }
}

// ---------------- MM: 64x32 tile, 512 blocks; writes next-layer LN stat partials ----
__global__ __launch_bounds__(256, 2) void mm_kernel(
    const bf16* __restrict__ A,    // g [L,H] bf16
    const bf16* __restrict__ W1,   // out_w  [H,H] (n,k) bf16
    const bf16* __restrict__ W2,   // out2_w [H,H] bf16
    const float* __restrict__ bias1, const float* __restrict__ bias2,
    float* __restrict__ Hio, float2* __restrict__ statP, int doStats) {
    const int w = threadIdx.x >> 6, lane = threadIdx.x & 63;
    const int wm = w >> 1, wn = w & 1;
    const int bm = blockIdx.x >> 4, bn = blockIdx.x & 15;
    const int mW = bm * 64 + wm * 32;
    const int nW = bn * 32 + wn * 16;
    const int lrow = lane & 15, quad = lane >> 4;

    floatx4 acc1[2] = {{0.f,0.f,0.f,0.f},{0.f,0.f,0.f,0.f}};
    floatx4 acc2[2] = {{0.f,0.f,0.f,0.f},{0.f,0.f,0.f,0.f}};
    for (int k0 = 0; k0 < HD; k0 += 32) {
        int kk = k0 + quad * 8;
        bf16x8 a0 = *(const bf16x8*)(A + (size_t)(mW + lrow) * HD + kk);
        bf16x8 a1 = *(const bf16x8*)(A + (size_t)(mW + 16 + lrow) * HD + kk);
        bf16x8 p0 = *(const bf16x8*)(W1 + (size_t)(nW + lrow) * HD + kk);
        bf16x8 q0 = *(const bf16x8*)(W2 + (size_t)(nW + lrow) * HD + kk);
        acc1[0] = __builtin_amdgcn_mfma_f32_16x16x32_bf16(a0, p0, acc1[0], 0, 0, 0);
        acc1[1] = __builtin_amdgcn_mfma_f32_16x16x32_bf16(a1, p0, acc1[1], 0, 0, 0);
        acc2[0] = __builtin_amdgcn_mfma_f32_16x16x32_bf16(a0, q0, acc2[0], 0, 0, 0);
        acc2[1] = __builtin_amdgcn_mfma_f32_16x16x32_bf16(a1, q0, acc2[1], 0, 0, 0);
    }
    int jj = nW + lrow;
    float bb1 = bias1[jj], bb2 = bias2[jj];
    float hn_[2][4];
#pragma unroll
    for (int fm = 0; fm < 2; ++fm)
#pragma unroll
        for (int r = 0; r < 4; ++r) {
            int t = mW + fm * 16 + quad * 4 + r;
            float z1 = acc1[fm][r] + bb1;
            float z2 = acc2[fm][r] + bb2;
            float v = Hio[(size_t)t * HD + jj] + z1 / (1.f + __expf(-z2));
            Hio[(size_t)t * HD + jj] = v;
            hn_[fm][r] = v;
        }
    if (doStats) {                                  // per-16-col (sum, sumsq) partials
#pragma unroll
        for (int fm = 0; fm < 2; ++fm)
#pragma unroll
            for (int r = 0; r < 4; ++r) {
                float s = hn_[fm][r], s2 = s * s;
#pragma unroll
                for (int m = 1; m <= 8; m <<= 1) {
                    s  += __shfl_xor(s, m, 64);
                    s2 += __shfl_xor(s2, m, 64);
                }
                if (lrow == 0) {
                    int t = mW + fm * 16 + quad * 4 + r;
                    statP[(size_t)t * 32 + (nW >> 4)] = make_float2(s, s2);
                }
            }
    }
}

// ---------------- decoder: out[L,3] ----------------
__global__ __launch_bounds__(192) void dec_kernel(
    const float* __restrict__ h, const float* __restrict__ w,
    const float* __restrict__ b, float* __restrict__ out) {
    int j = threadIdx.x >> 6, lane = threadIdx.x & 63;
    int t = blockIdx.x;
    const float* hp = h + (size_t)t * HD + lane * 8;
    float v[8];
    *(float4*)(v)     = *(const float4*)(hp);
    *(float4*)(v + 4) = *(const float4*)(hp + 4);
    float w8[8];
    *(float4*)(w8)     = *(const float4*)(w + j * HD + lane * 8);
    *(float4*)(w8 + 4) = *(const float4*)(w + j * HD + lane * 8 + 4);
    float s = 0.f;
#pragma unroll
    for (int e = 0; e < 8; ++e) s = fmaf(v[e], w8[e], s);
#pragma unroll
    for (int m = 32; m; m >>= 1) s += __shfl_xor(s, m, 64);
    if (lane == 0) out[t * 3 + j] = s + b[j];
}

extern "C" void kernel_launch(void* const* d_in, const int* in_sizes, int n_in,
                              void* d_out, int out_size, void* d_ws, size_t ws_size,
                              hipStream_t stream) {
    const float* x   = (const float*)d_in[0];
    const float* ew  = (const float*)d_in[1];
    const float* eb  = (const float*)d_in[2];
    const float* dw  = (const float*)d_in[3];
    const float* db  = (const float*)d_in[4];
    const float* nw  = (const float*)d_in[5];
    const float* nb  = (const float*)d_in[6];
    const float* lre = (const float*)d_in[7];
    const float* lim = (const float*)d_in[8];
    const float* bre = (const float*)d_in[9];
    const float* bim = (const float*)d_in[10];
    const float* cre = (const float*)d_in[11];
    const float* cim = (const float*)d_in[12];
    const float* dd  = (const float*)d_in[13];
    const float* ls  = (const float*)d_in[14];
    const float* ow  = (const float*)d_in[15];
    const float* ob  = (const float*)d_in[16];
    const float* o2w = (const float*)d_in[17];
    const float* o2b = (const float*)d_in[18];

    char* ws = (char*)d_ws;
    float*  h     = (float*)ws;                           // 4 MB   [L,H]
    float2* f     = (float2*)(ws + (4  << 20));           // 8.4 MB [NCHK][NST][HD]
    bf16*   g     = (bf16*)(ws + (16 << 20));             // 2 MB   [L,H] bf16
    bf16*   wb    = (bf16*)(ws + (18 << 20));             // 4 MB   bf16 weights
    float2* cA    = (float2*)(ws + (22 << 20));           // 512 KB [4][NST][HD]
    float2* cB    = (float2*)(ws + (22 << 20) + (512 << 10));
    float2* cC    = (float2*)(ws + (23 << 20));
    float2* cAp   = (float2*)(ws + (23 << 20) + (512 << 10));
    float2* statP = (float2*)(ws + (24 << 20));           // 512 KB [L][32] (sum,sumsq)

    setup_kernel<<<5376, 256, 0, stream>>>(x, ew, eb, ow, o2w,
                                           lre, lim, bre, bim, cre, cim, ls,
                                           h, wb, cA, cB, cC, cAp, statP);
    for (int lay = 0; lay < 4; ++lay) {
        int oH = lay * HD;
        p1_kernel<<<dim3(HD / 16, NCHK / 4), 256, 0, stream>>>(
            h, statP, nw + oH, nb + oH, cA, cB, f, lay);
        p2_kernel<<<64, 256, 0, stream>>>(f, cAp, lay);
        p3_kernel<<<dim3(HD / 16, NCHK / 4), 256, 0, stream>>>(
            h, statP, nw + oH, nb + oH, f, cA, cB, cC, dd, g, lay);
        mm_kernel<<<512, 256, 0, stream>>>(
            g, wb + lay * HH, wb + 4 * HH + lay * HH, ob + oH, o2b + oH, h,
            statP, lay < 3 ? 1 : 0);
    }
    dec_kernel<<<LSEQ, 192, 0, stream>>>(h, dw, db, (float*)d_out);
}